// Round 11
// baseline (16.185 us; speedup 1.0000x reference)
//
#include <hip/hip_runtime.h>
#include <math.h>

#define TPB 256   // 4 waves per block; each wave handles TWO images (shared W reads); 8 img/block

typedef __fp16 half2v __attribute__((ext_vector_type(2)));
typedef __fp16 half4v __attribute__((ext_vector_type(4)));
typedef __fp16 half8v __attribute__((ext_vector_type(8)));

// DPP-based wave64 sum (pure VALU). ctrl/rmask must be literal constants.
template <int CTRL, int RMASK>
__device__ inline float dpp_add(float v) {
    int t = __builtin_amdgcn_update_dpp(0, __float_as_int(v), CTRL, RMASK, 0xf, false);
    return v + __int_as_float(t);
}
__device__ inline float wave_sum_bcast(float v) {
    v = dpp_add<0x111, 0xf>(v);  // row_shr:1
    v = dpp_add<0x112, 0xf>(v);  // row_shr:2
    v = dpp_add<0x114, 0xf>(v);  // row_shr:4
    v = dpp_add<0x118, 0xf>(v);  // row_shr:8
    v = dpp_add<0x142, 0xa>(v);  // row_bcast15
    v = dpp_add<0x143, 0xc>(v);  // row_bcast31 -> lane 63 = total
    return __int_as_float(__builtin_amdgcn_readlane(__float_as_int(v), 63));
}

#if __has_builtin(__builtin_amdgcn_fdot2)
#define HAVE_FDOT2 1
#else
#define HAVE_FDOT2 0
#endif

__global__ __launch_bounds__(TPB, 1) void quanv_one_kernel(
    const float* __restrict__ x,       // (B,784)
    const float* __restrict__ params,  // (L,4)
    const float* __restrict__ W,       // (10,1568)
    const float* __restrict__ bias,    // (10,)
    float* __restrict__ out,           // (B,10)
    int B, int L)
{
    // f16 packed weights: wlds[(c*196+t)*8 + k]; k<4: W[c][4t+k] (quantum),
    // k>=4: W[c][784 + cf] where cf's pixel is 4t+(k-4) (classical, pixel order)
    __shared__ __align__(16) __fp16 wlds[15680];
    __shared__ __align__(16) float umat[32];   // folded U_u[16], U_v[16]

    const int tid  = threadIdx.x;
    const int lane = tid & 63;
    const int wv   = tid >> 6;

    // ---- cooperative W pack: coalesced float4 source reads, LDS-side scatter ----
    for (int g = tid; g < 3920; g += TPB) {
        if (g < 1960) {
            int e  = g * 4;                // flat over 10*784 (quantum half)
            int c  = e / 784;
            int q0 = e - c * 784;
            float4 q = *(const float4*)(W + c * 1568 + q0);
            half4v o;
            o[0] = (__fp16)q.x; o[1] = (__fp16)q.y;
            o[2] = (__fp16)q.z; o[3] = (__fp16)q.w;
            *(half4v*)(wlds + (c * 196 + (q0 >> 2)) * 8) = o;   // ds_write_b64
        } else {
            int e   = (g - 1960) * 4;      // flat over 10*784 (classical half)
            int c   = e / 784;
            int cf0 = e - c * 784;
            float4 q = *(const float4*)(W + c * 1568 + 784 + cf0);
            float qv[4] = {q.x, q.y, q.z, q.w};
#pragma unroll
            for (int d = 0; d < 4; ++d) {
                int cf = cf0 + d;
                int a  = cf / 196;
                int r1 = cf - a * 196;
                int bb = r1 / 49;
                int r2 = r1 - bb * 49;
                int i  = r2 / 7;
                int j  = r2 - i * 7;
                int t  = 28 * i + 7 * a + j;        // pixel>>2
                wlds[(c * 196 + t) * 8 + 4 + bb] = (__fp16)qv[d];
            }
        }
    }

    // ---- fold variational layers into 4x4 U per factor (lanes 0,1 of wave 0) ----
    if (tid < 2) {
        const int f = tid;                // 0: wires{0,1}, 1: wires{2,3}
        float M[16];
#pragma unroll
        for (int i = 0; i < 16; ++i) M[i] = (i % 5 == 0) ? 1.f : 0.f;
        for (int l = 0; l < L; ++l) {
            float A = params[4 * l + 2 * f + 0] * 0.5f;
            float C = __cosf(A), S = __sinf(A);
#pragma unroll
            for (int q = 0; q < 4; ++q) {  // RY hi wire: rows (0,2),(1,3)
                float a0 = M[q],     a2 = M[8 + q];
                M[q]      = C * a0 - S * a2;  M[8 + q]  = S * a0 + C * a2;
                float a1 = M[4 + q], a3 = M[12 + q];
                M[4 + q]  = C * a1 - S * a3;  M[12 + q] = S * a1 + C * a3;
            }
            A = params[4 * l + 2 * f + 1] * 0.5f;
            C = __cosf(A); S = __sinf(A);
#pragma unroll
            for (int q = 0; q < 4; ++q) {  // RY lo wire: rows (0,1),(2,3)
                float a0 = M[q],     a1 = M[4 + q];
                M[q]      = C * a0 - S * a1;  M[4 + q]  = S * a0 + C * a1;
                float a2 = M[8 + q], a3 = M[12 + q];
                M[8 + q]  = C * a2 - S * a3;  M[12 + q] = S * a2 + C * a3;
            }
#pragma unroll
            for (int q = 0; q < 4; ++q) {  // CNOT: swap rows 2,3
                float tm = M[8 + q]; M[8 + q] = M[12 + q]; M[12 + q] = tm;
            }
        }
#pragma unroll
        for (int i = 0; i < 16; ++i) umat[f * 16 + i] = M[i];
    }

    __syncthreads();   // the only block barrier

    const int img0 = blockIdx.x * 8 + wv * 2;
    const int img1 = img0 + 1;
    const float* xa = x + (size_t)((img0 < B) ? img0 : (B - 1)) * 784;
    const float* xb = x + (size_t)((img1 < B) ? img1 : (B - 1)) * 784;

    // U into registers (LDS broadcast reads)
    float Um[32];
#pragma unroll
    for (int j = 0; j < 8; ++j) ((float4*)Um)[j] = ((const float4*)umat)[j];

    // ---- prefetch all pixel data for both images (one latency hit) ----
    float2 topA[4], botA[4], topB[4], botB[4];
    float4 cimA[4], cimB[4];
#pragma unroll
    for (int r = 0; r < 4; ++r) {
        int t = r * 64 + lane;
        if (t < 196) {
            int pi = t / 14, pj = t - pi * 14;
            int po = 56 * pi + 2 * pj;
            topA[r] = *(const float2*)(xa + po);
            botA[r] = *(const float2*)(xa + po + 28);
            cimA[r] = *(const float4*)(xa + 4 * t);
            topB[r] = *(const float2*)(xb + po);
            botB[r] = *(const float2*)(xb + po + 28);
            cimB[r] = *(const float4*)(xb + 4 * t);
        }
    }

    float accA[10], accB[10];
#pragma unroll
    for (int c = 0; c < 10; ++c) { accA[c] = 0.f; accB[c] = 0.f; }

#pragma unroll
    for (int r = 0; r < 4; ++r) {
        int t = r * 64 + lane;
        if (t < 196) {
            // ---- features, image A ----
            float c0 = __cosf(0.5f * topA[r].x), s0 = __sinf(0.5f * topA[r].x);
            float c1 = __cosf(0.5f * topA[r].y), s1 = __sinf(0.5f * topA[r].y);
            float c2 = __cosf(0.5f * botA[r].x), s2 = __sinf(0.5f * botA[r].x);
            float c3 = __cosf(0.5f * botA[r].y), s3 = __sinf(0.5f * botA[r].y);
            float ui0 = c0 * c1, ui1 = c0 * s1, ui2 = s0 * c1, ui3 = s0 * s1;
            float vi0 = c2 * c3, vi1 = c2 * s3, vi2 = s2 * c3, vi3 = s2 * s3;
            float uf0 = fmaf(Um[0],  ui0, fmaf(Um[1],  ui1, fmaf(Um[2],  ui2, Um[3]  * ui3)));
            float uf1 = fmaf(Um[4],  ui0, fmaf(Um[5],  ui1, fmaf(Um[6],  ui2, Um[7]  * ui3)));
            float uf2 = fmaf(Um[8],  ui0, fmaf(Um[9],  ui1, fmaf(Um[10], ui2, Um[11] * ui3)));
            float uf3 = fmaf(Um[12], ui0, fmaf(Um[13], ui1, fmaf(Um[14], ui2, Um[15] * ui3)));
            float vf0 = fmaf(Um[16], vi0, fmaf(Um[17], vi1, fmaf(Um[18], vi2, Um[19] * vi3)));
            float vf1 = fmaf(Um[20], vi0, fmaf(Um[21], vi1, fmaf(Um[22], vi2, Um[23] * vi3)));
            float vf2 = fmaf(Um[24], vi0, fmaf(Um[25], vi1, fmaf(Um[26], vi2, Um[27] * vi3)));
            float vf3 = fmaf(Um[28], vi0, fmaf(Um[29], vi1, fmaf(Um[30], vi2, Um[31] * vi3)));
            float p0 = uf0 * uf0, p1 = uf1 * uf1, p2 = uf2 * uf2, p3 = uf3 * uf3;
            float q0 = vf0 * vf0, q1 = vf1 * vf1, q2 = vf2 * vf2, q3 = vf3 * vf3;
            half2v fa0 = __builtin_amdgcn_cvt_pkrtz((p0 + p1) - (p2 + p3), (p0 + p2) - (p1 + p3));
            half2v fa1 = __builtin_amdgcn_cvt_pkrtz((q0 + q1) - (q2 + q3), (q0 + q2) - (q1 + q3));
            half2v fa2 = __builtin_amdgcn_cvt_pkrtz(cimA[r].x, cimA[r].y);
            half2v fa3 = __builtin_amdgcn_cvt_pkrtz(cimA[r].z, cimA[r].w);

            // ---- features, image B ----
            c0 = __cosf(0.5f * topB[r].x); s0 = __sinf(0.5f * topB[r].x);
            c1 = __cosf(0.5f * topB[r].y); s1 = __sinf(0.5f * topB[r].y);
            c2 = __cosf(0.5f * botB[r].x); s2 = __sinf(0.5f * botB[r].x);
            c3 = __cosf(0.5f * botB[r].y); s3 = __sinf(0.5f * botB[r].y);
            ui0 = c0 * c1; ui1 = c0 * s1; ui2 = s0 * c1; ui3 = s0 * s1;
            vi0 = c2 * c3; vi1 = c2 * s3; vi2 = s2 * c3; vi3 = s2 * s3;
            uf0 = fmaf(Um[0],  ui0, fmaf(Um[1],  ui1, fmaf(Um[2],  ui2, Um[3]  * ui3)));
            uf1 = fmaf(Um[4],  ui0, fmaf(Um[5],  ui1, fmaf(Um[6],  ui2, Um[7]  * ui3)));
            uf2 = fmaf(Um[8],  ui0, fmaf(Um[9],  ui1, fmaf(Um[10], ui2, Um[11] * ui3)));
            uf3 = fmaf(Um[12], ui0, fmaf(Um[13], ui1, fmaf(Um[14], ui2, Um[15] * ui3)));
            vf0 = fmaf(Um[16], vi0, fmaf(Um[17], vi1, fmaf(Um[18], vi2, Um[19] * vi3)));
            vf1 = fmaf(Um[20], vi0, fmaf(Um[21], vi1, fmaf(Um[22], vi2, Um[23] * vi3)));
            vf2 = fmaf(Um[24], vi0, fmaf(Um[25], vi1, fmaf(Um[26], vi2, Um[27] * vi3)));
            vf3 = fmaf(Um[28], vi0, fmaf(Um[29], vi1, fmaf(Um[30], vi2, Um[31] * vi3)));
            p0 = uf0 * uf0; p1 = uf1 * uf1; p2 = uf2 * uf2; p3 = uf3 * uf3;
            q0 = vf0 * vf0; q1 = vf1 * vf1; q2 = vf2 * vf2; q3 = vf3 * vf3;
            half2v fb0 = __builtin_amdgcn_cvt_pkrtz((p0 + p1) - (p2 + p3), (p0 + p2) - (p1 + p3));
            half2v fb1 = __builtin_amdgcn_cvt_pkrtz((q0 + q1) - (q2 + q3), (q0 + q2) - (q1 + q3));
            half2v fb2 = __builtin_amdgcn_cvt_pkrtz(cimB[r].x, cimB[r].y);
            half2v fb3 = __builtin_amdgcn_cvt_pkrtz(cimB[r].z, cimB[r].w);

            // ---- dot: ONE W read serves both images ----
#pragma unroll
            for (int c = 0; c < 10; ++c) {
                half8v w = *(const half8v*)(wlds + (c * 196 + t) * 8);
                half2v w0 = __builtin_shufflevector(w, w, 0, 1);
                half2v w1 = __builtin_shufflevector(w, w, 2, 3);
                half2v w2 = __builtin_shufflevector(w, w, 4, 5);
                half2v w3 = __builtin_shufflevector(w, w, 6, 7);
#if HAVE_FDOT2
                float a = accA[c];
                a = __builtin_amdgcn_fdot2(fa0, w0, a, false);
                a = __builtin_amdgcn_fdot2(fa1, w1, a, false);
                a = __builtin_amdgcn_fdot2(fa2, w2, a, false);
                a = __builtin_amdgcn_fdot2(fa3, w3, a, false);
                accA[c] = a;
                float b = accB[c];
                b = __builtin_amdgcn_fdot2(fb0, w0, b, false);
                b = __builtin_amdgcn_fdot2(fb1, w1, b, false);
                b = __builtin_amdgcn_fdot2(fb2, w2, b, false);
                b = __builtin_amdgcn_fdot2(fb3, w3, b, false);
                accB[c] = b;
#else
                float a = accA[c];
                a = fmaf((float)fa0[0], (float)w0[0], a); a = fmaf((float)fa0[1], (float)w0[1], a);
                a = fmaf((float)fa1[0], (float)w1[0], a); a = fmaf((float)fa1[1], (float)w1[1], a);
                a = fmaf((float)fa2[0], (float)w2[0], a); a = fmaf((float)fa2[1], (float)w2[1], a);
                a = fmaf((float)fa3[0], (float)w3[0], a); a = fmaf((float)fa3[1], (float)w3[1], a);
                accA[c] = a;
                float b = accB[c];
                b = fmaf((float)fb0[0], (float)w0[0], b); b = fmaf((float)fb0[1], (float)w0[1], b);
                b = fmaf((float)fb1[0], (float)w1[0], b); b = fmaf((float)fb1[1], (float)w1[1], b);
                b = fmaf((float)fb2[0], (float)w2[0], b); b = fmaf((float)fb2[1], (float)w2[1], b);
                b = fmaf((float)fb3[0], (float)w3[0], b); b = fmaf((float)fb3[1], (float)w3[1], b);
                accB[c] = b;
#endif
            }
        }
    }

    // ---- DPP wave reductions + bias ----
    float lgA[10], lgB[10];
#pragma unroll
    for (int c = 0; c < 10; ++c) lgA[c] = wave_sum_bcast(accA[c]) + bias[c];
#pragma unroll
    for (int c = 0; c < 10; ++c) lgB[c] = wave_sum_bcast(accB[c]) + bias[c];

    // ---- softmax + store, image A ----
    if (img0 < B) {
        float m = lgA[0];
#pragma unroll
        for (int c = 1; c < 10; ++c) m = fmaxf(m, lgA[c]);
        float se = 0.f;
#pragma unroll
        for (int c = 0; c < 10; ++c) se += __expf(lgA[c] - m);
        float lse = __logf(se) + m;
        if (lane < 10) {
            float o = lgA[0];
            o = (lane == 1) ? lgA[1] : o;
            o = (lane == 2) ? lgA[2] : o;
            o = (lane == 3) ? lgA[3] : o;
            o = (lane == 4) ? lgA[4] : o;
            o = (lane == 5) ? lgA[5] : o;
            o = (lane == 6) ? lgA[6] : o;
            o = (lane == 7) ? lgA[7] : o;
            o = (lane == 8) ? lgA[8] : o;
            o = (lane == 9) ? lgA[9] : o;
            out[(size_t)img0 * 10 + lane] = o - lse;
        }
    }
    // ---- softmax + store, image B ----
    if (img1 < B) {
        float m = lgB[0];
#pragma unroll
        for (int c = 1; c < 10; ++c) m = fmaxf(m, lgB[c]);
        float se = 0.f;
#pragma unroll
        for (int c = 0; c < 10; ++c) se += __expf(lgB[c] - m);
        float lse = __logf(se) + m;
        if (lane < 10) {
            float o = lgB[0];
            o = (lane == 1) ? lgB[1] : o;
            o = (lane == 2) ? lgB[2] : o;
            o = (lane == 3) ? lgB[3] : o;
            o = (lane == 4) ? lgB[4] : o;
            o = (lane == 5) ? lgB[5] : o;
            o = (lane == 6) ? lgB[6] : o;
            o = (lane == 7) ? lgB[7] : o;
            o = (lane == 8) ? lgB[8] : o;
            o = (lane == 9) ? lgB[9] : o;
            out[(size_t)img1 * 10 + lane] = o - lse;
        }
    }
}

extern "C" void kernel_launch(void* const* d_in, const int* in_sizes, int n_in,
                              void* d_out, int out_size, void* d_ws, size_t ws_size,
                              hipStream_t stream) {
    const float* x      = (const float*)d_in[0];
    const float* params = (const float*)d_in[1];
    const float* W      = (const float*)d_in[2];
    const float* bias   = (const float*)d_in[3];
    float* out          = (float*)d_out;

    const int B = in_sizes[0] / 784;
    const int L = in_sizes[1] / 4;

    const int nblk = (B + 7) / 8;   // 8 images per block (2 per wave)
    quanv_one_kernel<<<dim3(nblk), dim3(TPB), 0, stream>>>(x, params, W, bias, out, B, L);
}

// Round 12
// 13.080 us; speedup vs baseline: 1.2373x; 1.2373x over previous
//
#include <hip/hip_runtime.h>
#include <math.h>

#define TPB 512   // 8 waves per block, one image per wave; grid = ceil(B/8) -> 1 block/CU at B=2048

typedef __fp16 half2v __attribute__((ext_vector_type(2)));
typedef __fp16 half4v __attribute__((ext_vector_type(4)));
typedef __fp16 half8v __attribute__((ext_vector_type(8)));

// DPP-based wave64 sum (pure VALU). ctrl/rmask must be literal constants.
template <int CTRL, int RMASK>
__device__ inline float dpp_add(float v) {
    int t = __builtin_amdgcn_update_dpp(0, __float_as_int(v), CTRL, RMASK, 0xf, false);
    return v + __int_as_float(t);
}
__device__ inline float wave_sum_bcast(float v) {
    v = dpp_add<0x111, 0xf>(v);  // row_shr:1
    v = dpp_add<0x112, 0xf>(v);  // row_shr:2
    v = dpp_add<0x114, 0xf>(v);  // row_shr:4
    v = dpp_add<0x118, 0xf>(v);  // row_shr:8
    v = dpp_add<0x142, 0xa>(v);  // row_bcast15
    v = dpp_add<0x143, 0xc>(v);  // row_bcast31 -> lane 63 = total
    return __int_as_float(__builtin_amdgcn_readlane(__float_as_int(v), 63));
}

#if __has_builtin(__builtin_amdgcn_fdot2)
#define HAVE_FDOT2 1
#else
#define HAVE_FDOT2 0
#endif

__global__ __launch_bounds__(TPB, 2) void quanv_one_kernel(
    const float* __restrict__ x,       // (B,784)
    const float* __restrict__ params,  // (L,4)
    const float* __restrict__ W,       // (10,1568)
    const float* __restrict__ bias,    // (10,)
    float* __restrict__ out,           // (B,10)
    int B, int L)
{
    // f16 packed weights: wlds[(c*196+t)*8 + k]; k<4: W[c][4t+k] (quantum),
    // k>=4: W[c][784 + cf] where cf's pixel is 4t+(k-4) (classical, pixel order)
    __shared__ __align__(16) __fp16 wlds[15680];
    __shared__ __align__(16) float umat[32];   // folded U_u[16], U_v[16]

    const int tid  = threadIdx.x;
    const int lane = tid & 63;
    const int wv   = tid >> 6;

    // ---- cooperative W pack: coalesced float4 source reads, LDS-side scatter ----
    for (int g = tid; g < 3920; g += TPB) {
        if (g < 1960) {
            int e  = g * 4;                // flat over 10*784 (quantum half)
            int c  = e / 784;
            int q0 = e - c * 784;
            float4 q = *(const float4*)(W + c * 1568 + q0);
            half4v o;
            o[0] = (__fp16)q.x; o[1] = (__fp16)q.y;
            o[2] = (__fp16)q.z; o[3] = (__fp16)q.w;
            *(half4v*)(wlds + (c * 196 + (q0 >> 2)) * 8) = o;   // ds_write_b64
        } else {
            int e   = (g - 1960) * 4;      // flat over 10*784 (classical half)
            int c   = e / 784;
            int cf0 = e - c * 784;
            float4 q = *(const float4*)(W + c * 1568 + 784 + cf0);
            float qv[4] = {q.x, q.y, q.z, q.w};
#pragma unroll
            for (int d = 0; d < 4; ++d) {
                int cf = cf0 + d;
                int a  = cf / 196;
                int r1 = cf - a * 196;
                int bb = r1 / 49;
                int r2 = r1 - bb * 49;
                int i  = r2 / 7;
                int j  = r2 - i * 7;
                int t  = 28 * i + 7 * a + j;        // pixel>>2
                wlds[(c * 196 + t) * 8 + 4 + bb] = (__fp16)qv[d];
            }
        }
    }

    // ---- fold variational layers into 4x4 U per factor (lanes 0,1 of wave 0) ----
    if (tid < 2) {
        const int f = tid;                // 0: wires{0,1}, 1: wires{2,3}
        float M[16];
#pragma unroll
        for (int i = 0; i < 16; ++i) M[i] = (i % 5 == 0) ? 1.f : 0.f;
        for (int l = 0; l < L; ++l) {
            float A = params[4 * l + 2 * f + 0] * 0.5f;
            float C = __cosf(A), S = __sinf(A);
#pragma unroll
            for (int q = 0; q < 4; ++q) {  // RY hi wire: rows (0,2),(1,3)
                float a0 = M[q],     a2 = M[8 + q];
                M[q]      = C * a0 - S * a2;  M[8 + q]  = S * a0 + C * a2;
                float a1 = M[4 + q], a3 = M[12 + q];
                M[4 + q]  = C * a1 - S * a3;  M[12 + q] = S * a1 + C * a3;
            }
            A = params[4 * l + 2 * f + 1] * 0.5f;
            C = __cosf(A); S = __sinf(A);
#pragma unroll
            for (int q = 0; q < 4; ++q) {  // RY lo wire: rows (0,1),(2,3)
                float a0 = M[q],     a1 = M[4 + q];
                M[q]      = C * a0 - S * a1;  M[4 + q]  = S * a0 + C * a1;
                float a2 = M[8 + q], a3 = M[12 + q];
                M[8 + q]  = C * a2 - S * a3;  M[12 + q] = S * a2 + C * a3;
            }
#pragma unroll
            for (int q = 0; q < 4; ++q) {  // CNOT: swap rows 2,3
                float tm = M[8 + q]; M[8 + q] = M[12 + q]; M[12 + q] = tm;
            }
        }
#pragma unroll
        for (int i = 0; i < 16; ++i) umat[f * 16 + i] = M[i];
    }

    __syncthreads();   // the only block barrier

    const int img = blockIdx.x * 8 + wv;
    if (img >= B) return;

    // U into registers (LDS broadcast reads)
    float Um[32];
#pragma unroll
    for (int j = 0; j < 8; ++j) ((float4*)Um)[j] = ((const float4*)umat)[j];

    const float* xb = x + (size_t)img * 784;

    // ---- prefetch ALL pixel data into registers (single latency exposure) ----
    float2 top[4], bot[4];
    float4 cim[4];
#pragma unroll
    for (int r = 0; r < 4; ++r) {
        int t = r * 64 + lane;
        if (t < 196) {
            int pi = t / 14, pj = t - pi * 14;
            int po = 56 * pi + 2 * pj;
            top[r] = *(const float2*)(xb + po);
            bot[r] = *(const float2*)(xb + po + 28);
            cim[r] = *(const float4*)(xb + 4 * t);
        }
    }

    float acc[10];
#pragma unroll
    for (int c = 0; c < 10; ++c) acc[c] = 0.f;

#pragma unroll
    for (int r = 0; r < 4; ++r) {
        int t = r * 64 + lane;
        if (t < 196) {
            float c0 = __cosf(0.5f * top[r].x), s0 = __sinf(0.5f * top[r].x);
            float c1 = __cosf(0.5f * top[r].y), s1 = __sinf(0.5f * top[r].y);
            float c2 = __cosf(0.5f * bot[r].x), s2 = __sinf(0.5f * bot[r].x);
            float c3 = __cosf(0.5f * bot[r].y), s3 = __sinf(0.5f * bot[r].y);

            float ui0 = c0 * c1, ui1 = c0 * s1, ui2 = s0 * c1, ui3 = s0 * s1;
            float vi0 = c2 * c3, vi1 = c2 * s3, vi2 = s2 * c3, vi3 = s2 * s3;

            float uf0 = fmaf(Um[0],  ui0, fmaf(Um[1],  ui1, fmaf(Um[2],  ui2, Um[3]  * ui3)));
            float uf1 = fmaf(Um[4],  ui0, fmaf(Um[5],  ui1, fmaf(Um[6],  ui2, Um[7]  * ui3)));
            float uf2 = fmaf(Um[8],  ui0, fmaf(Um[9],  ui1, fmaf(Um[10], ui2, Um[11] * ui3)));
            float uf3 = fmaf(Um[12], ui0, fmaf(Um[13], ui1, fmaf(Um[14], ui2, Um[15] * ui3)));
            float vf0 = fmaf(Um[16], vi0, fmaf(Um[17], vi1, fmaf(Um[18], vi2, Um[19] * vi3)));
            float vf1 = fmaf(Um[20], vi0, fmaf(Um[21], vi1, fmaf(Um[22], vi2, Um[23] * vi3)));
            float vf2 = fmaf(Um[24], vi0, fmaf(Um[25], vi1, fmaf(Um[26], vi2, Um[27] * vi3)));
            float vf3 = fmaf(Um[28], vi0, fmaf(Um[29], vi1, fmaf(Um[30], vi2, Um[31] * vi3)));

            float p0 = uf0 * uf0, p1 = uf1 * uf1, p2 = uf2 * uf2, p3 = uf3 * uf3;
            float q0 = vf0 * vf0, q1 = vf1 * vf1, q2 = vf2 * vf2, q3 = vf3 * vf3;
            float z0 = (p0 + p1) - (p2 + p3);
            float z1 = (p0 + p2) - (p1 + p3);
            float z2 = (q0 + q1) - (q2 + q3);
            float z3 = (q0 + q2) - (q1 + q3);

            half2v f0 = __builtin_amdgcn_cvt_pkrtz(z0, z1);
            half2v f1 = __builtin_amdgcn_cvt_pkrtz(z2, z3);
            half2v f2 = __builtin_amdgcn_cvt_pkrtz(cim[r].x, cim[r].y);
            half2v f3 = __builtin_amdgcn_cvt_pkrtz(cim[r].z, cim[r].w);

#pragma unroll
            for (int c = 0; c < 10; ++c) {
                half8v w = *(const half8v*)(wlds + (c * 196 + t) * 8);
                half2v w0 = __builtin_shufflevector(w, w, 0, 1);
                half2v w1 = __builtin_shufflevector(w, w, 2, 3);
                half2v w2 = __builtin_shufflevector(w, w, 4, 5);
                half2v w3 = __builtin_shufflevector(w, w, 6, 7);
                float a = acc[c];
#if HAVE_FDOT2
                a = __builtin_amdgcn_fdot2(f0, w0, a, false);
                a = __builtin_amdgcn_fdot2(f1, w1, a, false);
                a = __builtin_amdgcn_fdot2(f2, w2, a, false);
                a = __builtin_amdgcn_fdot2(f3, w3, a, false);
#else
                a = fmaf((float)f0[0], (float)w0[0], a); a = fmaf((float)f0[1], (float)w0[1], a);
                a = fmaf((float)f1[0], (float)w1[0], a); a = fmaf((float)f1[1], (float)w1[1], a);
                a = fmaf((float)f2[0], (float)w2[0], a); a = fmaf((float)f2[1], (float)w2[1], a);
                a = fmaf((float)f3[0], (float)w3[0], a); a = fmaf((float)f3[1], (float)w3[1], a);
#endif
                acc[c] = a;
            }
        }
    }

    // ---- DPP wave reduction (all-lane uniform results) ----
    float l0 = wave_sum_bcast(acc[0]) + bias[0];
    float l1 = wave_sum_bcast(acc[1]) + bias[1];
    float l2 = wave_sum_bcast(acc[2]) + bias[2];
    float l3 = wave_sum_bcast(acc[3]) + bias[3];
    float l4 = wave_sum_bcast(acc[4]) + bias[4];
    float l5 = wave_sum_bcast(acc[5]) + bias[5];
    float l6 = wave_sum_bcast(acc[6]) + bias[6];
    float l7 = wave_sum_bcast(acc[7]) + bias[7];
    float l8 = wave_sum_bcast(acc[8]) + bias[8];
    float l9 = wave_sum_bcast(acc[9]) + bias[9];

    float m = fmaxf(fmaxf(fmaxf(fmaxf(l0, l1), fmaxf(l2, l3)),
                          fmaxf(fmaxf(l4, l5), fmaxf(l6, l7))),
                    fmaxf(l8, l9));
    float se = __expf(l0 - m) + __expf(l1 - m) + __expf(l2 - m) + __expf(l3 - m) +
               __expf(l4 - m) + __expf(l5 - m) + __expf(l6 - m) + __expf(l7 - m) +
               __expf(l8 - m) + __expf(l9 - m);
    float lse = __logf(se) + m;

    if (lane < 10) {
        float o = l0 - lse;
        o = (lane == 1) ? l1 - lse : o;
        o = (lane == 2) ? l2 - lse : o;
        o = (lane == 3) ? l3 - lse : o;
        o = (lane == 4) ? l4 - lse : o;
        o = (lane == 5) ? l5 - lse : o;
        o = (lane == 6) ? l6 - lse : o;
        o = (lane == 7) ? l7 - lse : o;
        o = (lane == 8) ? l8 - lse : o;
        o = (lane == 9) ? l9 - lse : o;
        out[(size_t)img * 10 + lane] = o;
    }
}

extern "C" void kernel_launch(void* const* d_in, const int* in_sizes, int n_in,
                              void* d_out, int out_size, void* d_ws, size_t ws_size,
                              hipStream_t stream) {
    const float* x      = (const float*)d_in[0];
    const float* params = (const float*)d_in[1];
    const float* W      = (const float*)d_in[2];
    const float* bias   = (const float*)d_in[3];
    float* out          = (float*)d_out;

    const int B = in_sizes[0] / 784;
    const int L = in_sizes[1] / 4;

    const int nblk = (B + 7) / 8;
    quanv_one_kernel<<<dim3(nblk), dim3(TPB), 0, stream>>>(x, params, W, bias, out, B, L);
}